// Round 11
// baseline (150.694 us; speedup 1.0000x reference)
//
#include <hip/hip_runtime.h>
#include <hip/hip_bf16.h>

// Problem sizes (fixed): B=8, T=2048, H=64, M=32, S=20, E=3, IN=32
#define Bv  8
#define Tv  2048
#define Hv  64
#define Mv  32
#define Sv  20
#define Ev  3
#define INv 32
#define LOG2E 1.44269504088896340736f

typedef __attribute__((ext_vector_type(8))) _Float16 half8;
typedef __attribute__((ext_vector_type(2))) __fp16 fp16x2;
typedef __attribute__((ext_vector_type(4))) float float4v;

// ---------------------------------------------------------------------------
// Kernel 1: fused QKV (MFMA) -> 5 f16 planes + memories (e==0 blocks).
// Projection C[64 t][96 c] = hidden[64 t][64 h] @ W[64 h][96 c] via split-f16
// 3-term mfma_16x16x32_f16 (error ~2^-21 rel, fp32-grade for this use).
//   A-frags: read straight from global hidden ([t][h], h-contiguous).
//   B-frags: W staged once in LDS transposed Wt[c][h] f16 hi/lo, 128-B rows,
//            16B-block rotation ((blk + c) & 7) -> conflict-free ds_read_b128.
// Output layouts (per eb, per 64-row tile, 4 KB blocks) — identical to R10:
//   Qh/Ql : linear [T][32] (pre-scaled by LOG2E)
//   Kh/Kl : row r x 64 B, 16B-block q at ((q + r) & 3)
//   Vth   : row d (0..31) x 128 B, 16B-block c8 at ((c8 + d) & 7)
// ---------------------------------------------------------------------------
__global__ __launch_bounds__(256) void qkv_kernel(
    const float* __restrict__ hidden,
    const float* __restrict__ Wq,
    const float* __restrict__ Wk,
    const float* __restrict__ Wv,
    const float* __restrict__ x,        // [B*T, 32] for fused mem
    const float* __restrict__ memory,   // [20, 32]
    const float* __restrict__ iq,       // [32, 32]
    _Float16* __restrict__ Qh, _Float16* __restrict__ Ql,
    _Float16* __restrict__ Kh, _Float16* __restrict__ Kl,
    _Float16* __restrict__ Vth,
    float* __restrict__ memout)         // [B*T, 32]
{
    // Wt hi [0,12288) + Wt lo [12288,24576); output staging (20480 B) aliases
    // after the post-MFMA barrier.
    __shared__ __align__(16) char qsm[24576];
    __shared__ float sIQ[32][32];
    __shared__ float sM[20][32];

    int bid  = blockIdx.x;              // 768 = E*B*32
    int tile = bid & 31;
    int b    = (bid >> 5) & 7;
    int e    = bid >> 8;
    int tid  = threadIdx.x;
    int lane = tid & 63;
    int w    = tid >> 6;                // wave = m-tile (16 t-rows)
    int quad = lane >> 4;
    int l15  = lane & 15;
    size_t eb = (size_t)(e * Bv + b);

    // mem-fusion constants
    for (int i = tid; i < 32 * 32; i += 256) sIQ[i >> 5][i & 31] = iq[i];
    for (int i = tid; i < 20 * 32; i += 256) sM[i >> 5][i & 31] = memory[i];

    // ---- stage Wt[c][h] f16 hi/lo (96 x 64), swizzled 16B blocks
    {
        const float* wq = Wq + (size_t)e * Hv * Mv;
        const float* wk = Wk + (size_t)e * Hv * Mv;
        const float* wv = Wv + (size_t)e * Hv * Mv;
        for (int i = tid; i < 96 * 64; i += 256) {
            int c = i >> 6, h = i & 63;
            float v = (c < 32) ? wq[h * 32 + c]
                    : (c < 64) ? wk[h * 32 + (c - 32)]
                               : wv[h * 32 + (c - 64)];
            _Float16 h16 = (_Float16)v;
            _Float16 l16 = (_Float16)(v - (float)h16);
            int off = c * 128 + ((((h >> 3) + c) & 7) << 4) + (h & 7) * 2;
            *(_Float16*)(qsm + off)         = h16;
            *(_Float16*)(qsm + 12288 + off) = l16;
        }
    }
    __syncthreads();

    // ---- A-frags from global: wave w owns t rows tile*64 + w*16 + l15
    size_t grow = eb * Tv + (size_t)tile * 64 + w * 16 + l15;
    const float4* hrow = (const float4*)(hidden + grow * Hv);
    half8 aH[2], aL[2];
#pragma unroll
    for (int ks = 0; ks < 2; ++ks) {
        float4 v0 = hrow[ks * 8 + quad * 2];
        float4 v1 = hrow[ks * 8 + quad * 2 + 1];
        float av[8] = {v0.x, v0.y, v0.z, v0.w, v1.x, v1.y, v1.z, v1.w};
#pragma unroll
        for (int j = 0; j < 8; ++j) {
            _Float16 h16 = (_Float16)av[j];
            aH[ks][j] = h16;
            aL[ks][j] = (_Float16)(av[j] - (float)h16);
        }
    }

    // ---- 6 n-tiles x 2 k-steps x 3 split terms = 36 MFMA / wave
    float4v acc[6];
#pragma unroll
    for (int nt = 0; nt < 6; ++nt) acc[nt] = (float4v){0.f, 0.f, 0.f, 0.f};
#pragma unroll
    for (int ks = 0; ks < 2; ++ks) {
#pragma unroll
        for (int nt = 0; nt < 6; ++nt) {
            int cc = nt * 16 + l15;      // B-frag n = l15
            int sw = (((ks * 4 + quad) + cc) & 7) << 4;
            half8 bH = *(const half8*)(qsm + cc * 128 + sw);
            half8 bL = *(const half8*)(qsm + 12288 + cc * 128 + sw);
            acc[nt] = __builtin_amdgcn_mfma_f32_16x16x32_f16(aH[ks], bL, acc[nt], 0, 0, 0);
            acc[nt] = __builtin_amdgcn_mfma_f32_16x16x32_f16(aL[ks], bH, acc[nt], 0, 0, 0);
            acc[nt] = __builtin_amdgcn_mfma_f32_16x16x32_f16(aH[ks], bH, acc[nt], 0, 0, 0);
        }
    }

    // ---- stage f16 outputs into LDS (aliases Wt after barrier)
    __syncthreads();
    char* sQh = qsm;
    char* sQl = qsm + 4096;
    char* sKh = qsm + 8192;
    char* sKl = qsm + 12288;
    char* sVh = qsm + 16384;
#pragma unroll
    for (int nt = 0; nt < 6; ++nt) {
        int c = nt * 16 + l15;
#pragma unroll
        for (int r = 0; r < 4; ++r) {
            int row = w * 16 + quad * 4 + r;     // C layout: row=quad*4+r
            float v = acc[nt][r];
            if (c < 32) {
                v *= LOG2E;
                _Float16 h16 = (_Float16)v;
                _Float16 l16 = (_Float16)(v - (float)h16);
                *(_Float16*)(sQh + row * 64 + c * 2) = h16;
                *(_Float16*)(sQl + row * 64 + c * 2) = l16;
            } else if (c < 64) {
                _Float16 h16 = (_Float16)v;
                _Float16 l16 = (_Float16)(v - (float)h16);
                int m = c - 32, q = m >> 3, wi = m & 7;
                int off = row * 64 + (((q + row) & 3) << 4) + wi * 2;
                *(_Float16*)(sKh + off) = h16;
                *(_Float16*)(sKl + off) = l16;
            } else {
                int d = c - 64, c8 = row >> 3, wi = row & 7;
                int off = d * 128 + (((c8 + d) & 7) << 4) + wi * 2;
                *(_Float16*)(sVh + off) = (_Float16)v;
            }
        }
    }
    __syncthreads();

    // ---- coalesced stores: 5 planes x 4 KB contiguous
    size_t pb = eb * (size_t)Tv * 32 + (size_t)tile * 2048;   // f16 elems
    _Float16* dsts[5] = {Qh + pb, Ql + pb, Kh + pb, Kl + pb, Vth + pb};
#pragma unroll
    for (int pl = 0; pl < 5; ++pl)
        ((float4*)dsts[pl])[tid] = ((const float4*)(qsm + pl * 4096))[tid];

    // ---- fused mem: e==0 blocks compute memories for their 64 tokens
    if (e == 0 && tid < 64) {
        int t = b * Tv + tile * 64 + tid;
        const float4* xr = (const float4*)(x + (size_t)t * INv);
        float xv[32];
#pragma unroll
        for (int i = 0; i < 8; ++i) {
            float4 v = xr[i];
            xv[4*i] = v.x; xv[4*i+1] = v.y; xv[4*i+2] = v.z; xv[4*i+3] = v.w;
        }
        float qm[32];
#pragma unroll
        for (int m = 0; m < 32; ++m) qm[m] = 0.f;
        for (int i = 0; i < 32; ++i) {
            float xi = xv[i];
#pragma unroll
            for (int m4 = 0; m4 < 8; ++m4) {
                float4 wv = *(const float4*)&sIQ[i][m4 * 4];
                qm[4*m4]   = fmaf(xi, wv.x, qm[4*m4]);
                qm[4*m4+1] = fmaf(xi, wv.y, qm[4*m4+1]);
                qm[4*m4+2] = fmaf(xi, wv.z, qm[4*m4+2]);
                qm[4*m4+3] = fmaf(xi, wv.w, qm[4*m4+3]);
            }
        }
        float sc[20];
#pragma unroll
        for (int j = 0; j < 20; ++j) {
            float a2 = 0.f;
#pragma unroll
            for (int m = 0; m < 32; ++m) a2 = fmaf(qm[m], sM[j][m], a2);
            sc[j] = a2;
        }
        float mx = sc[0];
#pragma unroll
        for (int j = 1; j < 20; ++j) mx = fmaxf(mx, sc[j]);
        float psum = 0.f, p[20];
#pragma unroll
        for (int j = 0; j < 20; ++j) { p[j] = exp2f((sc[j] - mx) * LOG2E); psum += p[j]; }
        float inv = 1.0f / psum;
        float mo[32];
#pragma unroll
        for (int m = 0; m < 32; ++m) mo[m] = 0.f;
        for (int j = 0; j < 20; ++j) {
            float pj = p[j];
#pragma unroll
            for (int m = 0; m < 32; ++m) mo[m] = fmaf(pj, sM[j][m], mo[m]);
        }
        float4* outp = (float4*)(memout + (size_t)t * Mv);
#pragma unroll
        for (int m4 = 0; m4 < 8; ++m4) {
            float4 v;
            v.x = mo[4*m4] * inv; v.y = mo[4*m4+1] * inv;
            v.z = mo[4*m4+2] * inv; v.w = mo[4*m4+3] * inv;
            outp[m4] = v;
        }
    }
}

// ---------------------------------------------------------------------------
__device__ __forceinline__ void load_lds16(const _Float16* g, char* l) {
    __builtin_amdgcn_global_load_lds(
        (const __attribute__((address_space(1))) void*)g,
        (__attribute__((address_space(3))) void*)l, 16, 0, 0);
}

// ---------------------------------------------------------------------------
// Kernel 2: MFMA flash attention + cosine epilogue — R8/R10 kernel verbatim
// (measured 62-64 us; R9 variants regressed — do not touch).
// ---------------------------------------------------------------------------
__global__ __launch_bounds__(256, 1) void attn_kernel(
    const _Float16* __restrict__ Qh, const _Float16* __restrict__ Ql,
    const _Float16* __restrict__ Kh, const _Float16* __restrict__ Kl,
    const _Float16* __restrict__ Vth,
    const float* __restrict__ memv,
    float* __restrict__ out)
{
    __shared__ __align__(16) char smem[32768];
    const int PW = 24576;

    int bid  = blockIdx.x;              // 768
    int xcd  = bid & 7;
    int slot = bid >> 3;                // 0..95
    int tile = slot & 31;
    int ebi  = xcd + ((slot >> 5) << 3);  // 0..23
    int e    = ebi >> 3;
    int b    = ebi & 7;
    int tid  = threadIdx.x;
    int lane = tid & 63;
    int w    = tid >> 6;
    int quad = lane >> 4;
    int l15  = lane & 15;
    size_t eb = (size_t)ebi;
    int q0 = tile * 64 + w * 16;

    size_t qoff = (eb * Tv + (size_t)(q0 + l15)) * 32 + quad * 8;
    half8 qH = *(const half8*)(Qh + qoff);
    half8 qL = *(const half8*)(Ql + qoff);

    float4v O0 = {0.f, 0.f, 0.f, 0.f};  // O[q=quad*4+r][d=l15]
    float4v O1 = {0.f, 0.f, 0.f, 0.f};  // O[q=quad*4+r][d=16+l15]
    float m_run = -3.0e38f;

    size_t ebOff = eb * (size_t)Tv * 32;
    const _Float16* gp[3] = {Kh + ebOff, Kl + ebOff, Vth + ebOff};

#pragma unroll
    for (int j = 0; j < 3; ++j) {
        int idx = w * 3 + j, p = idx >> 2, k = idx & 3;
        load_lds16(gp[p] + (size_t)k * 512 + lane * 8,
                   smem + p * 4096 + k * 1024);
    }

    for (int c = 0; c < 32; ++c) {
        int pb = c & 1;
        __syncthreads();
        if (c + 1 < 32) {
#pragma unroll
            for (int j = 0; j < 3; ++j) {
                int idx = w * 3 + j, p = idx >> 2, k = idx & 3;
                load_lds16(gp[p] + (size_t)(c + 1) * 2048 + k * 512 + lane * 8,
                           smem + (pb ^ 1) * 12288 + p * 4096 + k * 1024);
            }
        }
        const char* base = smem + pb * 12288;

        float s[16];
        float cmax = -3.0e38f;
#pragma unroll
        for (int tau = 0; tau < 4; ++tau) {
            int r = tau * 16 + l15;
            int sw = ((quad + r) & 3) << 4;
            half8 aH = *(const half8*)(base + r * 64 + sw);
            half8 aL = *(const half8*)(base + 4096 + r * 64 + sw);
            float4v acc = {0.f, 0.f, 0.f, 0.f};
            acc = __builtin_amdgcn_mfma_f32_16x16x32_f16(aH, qL, acc, 0, 0, 0);
            acc = __builtin_amdgcn_mfma_f32_16x16x32_f16(aL, qH, acc, 0, 0, 0);
            acc = __builtin_amdgcn_mfma_f32_16x16x32_f16(aH, qH, acc, 0, 0, 0);
#pragma unroll
            for (int r2 = 0; r2 < 4; ++r2) {
                s[tau * 4 + r2] = acc[r2];
                cmax = fmaxf(cmax, acc[r2]);
            }
        }
        cmax = fmaxf(cmax, __shfl_xor(cmax, 16));
        cmax = fmaxf(cmax, __shfl_xor(cmax, 32));
        float mNew  = fmaxf(m_run, cmax);
        float alpha = exp2f(m_run - mNew);
#pragma unroll
        for (int i = 0; i < 16; ++i)
            s[i] = exp2f(s[i] - mNew);
        m_run = mNew;

#pragma unroll
        for (int r = 0; r < 4; ++r) {
            float ar = __shfl(alpha, quad * 4 + r, 16);
            O0[r] *= ar;
            O1[r] *= ar;
        }

        char* pw = smem + PW + w * 2048 + l15 * 128;
        int xr = l15 & 7;
#pragma unroll
        for (int tau = 0; tau < 4; ++tau) {
            fp16x2 h01 = __builtin_amdgcn_cvt_pkrtz(s[tau*4+0], s[tau*4+1]);
            fp16x2 h23 = __builtin_amdgcn_cvt_pkrtz(s[tau*4+2], s[tau*4+3]);
            uint2 u;
            u.x = __builtin_bit_cast(unsigned int, h01);
            u.y = __builtin_bit_cast(unsigned int, h23);
            int bi = tau * 2 + (quad >> 1);
            *(uint2*)(pw + ((bi ^ xr) << 4) + (quad & 1) * 8) = u;
        }
        __asm__ volatile("" ::: "memory");

#pragma unroll
        for (int ks = 0; ks < 2; ++ks) {
            int swv = ((ks * 4 + quad + l15) & 7) << 4;
            half8 pA  = *(const half8*)(pw + (((ks * 4 + quad) ^ xr) << 4));
            half8 v0H = *(const half8*)(base + 8192 + l15 * 128 + swv);
            half8 v1H = *(const half8*)(base + 8192 + (16 + l15) * 128 + swv);
            O0 = __builtin_amdgcn_mfma_f32_16x16x32_f16(pA, v0H, O0, 0, 0, 0);
            O1 = __builtin_amdgcn_mfma_f32_16x16x32_f16(pA, v1H, O1, 0, 0, 0);
        }
    }

    const float* mb = memv + (size_t)b * Tv * 32;
    float dotr[4], nor[4], nmr[4];
#pragma unroll
    for (int r = 0; r < 4; ++r) {
        int trow = q0 + quad * 4 + r;
        float mv0 = mb[(size_t)trow * 32 + l15];
        float mv1 = mb[(size_t)trow * 32 + 16 + l15];
        float d  = O0[r] * mv0 + O1[r] * mv1;
        float n  = O0[r] * O0[r] + O1[r] * O1[r];
        float nm = mv0 * mv0 + mv1 * mv1;
#pragma unroll
        for (int delta = 1; delta < 16; delta <<= 1) {
            d  += __shfl_xor(d,  delta);
            n  += __shfl_xor(n,  delta);
            nm += __shfl_xor(nm, delta);
        }
        dotr[r] = d; nor[r] = n; nmr[r] = nm;
    }
    if (l15 < 4) {
        int r = l15;
        float na = fmaxf(sqrtf(nmr[r]), 1e-8f);
        float nb = fmaxf(sqrtf(nor[r]), 1e-30f);
        float cosv = dotr[r] / (na * nb);
        int trow = q0 + quad * 4 + r;
        out[((size_t)b * Tv + trow) * Ev + e] = cosv;
    }
}

// ---------------------------------------------------------------------------
extern "C" void kernel_launch(void* const* d_in, const int* in_sizes, int n_in,
                              void* d_out, int out_size, void* d_ws, size_t ws_size,
                              hipStream_t stream) {
    const float* x      = (const float*)d_in[0];
    const float* hidden = (const float*)d_in[1];
    const float* memory = (const float*)d_in[2];
    const float* Wq     = (const float*)d_in[3];
    const float* Wk     = (const float*)d_in[4];
    const float* Wv     = (const float*)d_in[5];
    const float* iq     = (const float*)d_in[6];
    float* out          = (float*)d_out;           // [B,T,E] fp32

    char* ws = (char*)d_ws;
    const size_t PLANE = (size_t)Ev * Bv * Tv * 32 * 2;   // 3,145,728 B
    float*    memout = (float*)ws;
    _Float16* Qh  = (_Float16*)(ws + 2097152);
    _Float16* Ql  = (_Float16*)(ws + 2097152 + PLANE);
    _Float16* Kh  = (_Float16*)(ws + 2097152 + 2 * PLANE);
    _Float16* Kl  = (_Float16*)(ws + 2097152 + 3 * PLANE);
    _Float16* Vth = (_Float16*)(ws + 2097152 + 4 * PLANE);

    qkv_kernel<<<Ev * Bv * (Tv / 64), 256, 0, stream>>>(hidden, Wq, Wk, Wv,
                                                        x, memory, iq,
                                                        Qh, Ql, Kh, Kl, Vth, memout);
    attn_kernel<<<Ev * Bv * (Tv / 64), 256, 0, stream>>>(Qh, Ql, Kh, Kl, Vth,
                                                         memout, out);
}

// Round 13
// 147.616 us; speedup vs baseline: 1.0209x; 1.0209x over previous
//
#include <hip/hip_runtime.h>
#include <hip/hip_bf16.h>

// Problem sizes (fixed): B=8, T=2048, H=64, M=32, S=20, E=3, IN=32
#define Bv  8
#define Tv  2048
#define Hv  64
#define Mv  32
#define Sv  20
#define Ev  3
#define INv 32
#define LOG2E 1.44269504088896340736f

typedef __attribute__((ext_vector_type(8))) _Float16 half8;
typedef __attribute__((ext_vector_type(2))) __fp16 fp16x2;
typedef __attribute__((ext_vector_type(4))) float float4v;

// ---------------------------------------------------------------------------
// Kernel 1: fused QKV -> 5 f16 planes + memories (e==0 blocks).
// [R10 verbatim — best measured: total 148.5 us. R11's MFMA variant and R12's
// cooperative fusion both failed to beat it (150.7 / silent launch failure).]
// Layouts per eb, per 64-row tile (4 KB blocks):
//   Qh/Ql : linear [T][32]  (pre-scaled by LOG2E)
//   Kh/Kl : row r x 64 B, 16B-block q at ((q + r) & 3)
//   Vth   : row d (0..31) x 128 B (64 keys), 16B-block c8 at ((c8 + d) & 7)
// ---------------------------------------------------------------------------
__global__ __launch_bounds__(256) void qkv_kernel(
    const float* __restrict__ hidden,
    const float* __restrict__ Wq,
    const float* __restrict__ Wk,
    const float* __restrict__ Wv,
    const float* __restrict__ x,        // [B*T, 32] for fused mem
    const float* __restrict__ memory,   // [20, 32]
    const float* __restrict__ iq,       // [32, 32]
    _Float16* __restrict__ Qh, _Float16* __restrict__ Ql,
    _Float16* __restrict__ Kh, _Float16* __restrict__ Kl,
    _Float16* __restrict__ Vth,
    float* __restrict__ memout)         // [B*T, 32]
{
    __shared__ __align__(16) char qsm[43008];
    __shared__ float sIQ[32][32];
    __shared__ float sM[20][32];
    float* sHT = (float*)qsm;                    // [h][t] stride 68
    float* sW  = (float*)(qsm + 17408);          // [h][96+pad] stride 100

    int bid  = blockIdx.x;              // 768 = E*B*32
    int tile = bid & 31;
    int b    = (bid >> 5) & 7;
    int e    = bid >> 8;
    int tid  = threadIdx.x;
    size_t eb = (size_t)(e * Bv + b);
    size_t row0 = eb * Tv + (size_t)tile * 64;
    const float* hbase = hidden + row0 * Hv;

    for (int i = tid; i < 32 * 32; i += 256) sIQ[i >> 5][i & 31] = iq[i];
    for (int i = tid; i < 20 * 32; i += 256) sM[i >> 5][i & 31] = memory[i];

    {
        int r  = tid >> 2;
        int c4 = tid & 3;
#pragma unroll
        for (int hh = 0; hh < 4; ++hh) {
            int h4 = c4 + hh * 4;
            float4 v = ((const float4*)(hbase + (size_t)r * Hv))[h4];
            sHT[(h4*4+0)*68 + r] = v.x; sHT[(h4*4+1)*68 + r] = v.y;
            sHT[(h4*4+2)*68 + r] = v.z; sHT[(h4*4+3)*68 + r] = v.w;
        }
    }
    {
        const float* wq = Wq + (size_t)e * Hv * Mv;
        const float* wk = Wk + (size_t)e * Hv * Mv;
        const float* wv = Wv + (size_t)e * Hv * Mv;
        for (int i = tid; i < Hv * Mv; i += 256) {
            int h = i >> 5, m = i & 31;
            sW[h*100 + m]      = wq[i];
            sW[h*100 + 32 + m] = wk[i];
            sW[h*100 + 64 + m] = wv[i];
        }
    }
    __syncthreads();

    int ty = tid >> 4, tx = tid & 15;
    float acc[4][6];
#pragma unroll
    for (int i = 0; i < 4; ++i)
#pragma unroll
        for (int j = 0; j < 6; ++j) acc[i][j] = 0.f;

    for (int h = 0; h < 64; ++h) {
        float4 av = *(const float4*)&sHT[h*68 + ty * 4];
        float a[4] = {av.x, av.y, av.z, av.w};
        float bb[6];
#pragma unroll
        for (int j = 0; j < 6; ++j) bb[j] = sW[h*100 + tx * 6 + j];
#pragma unroll
        for (int i = 0; i < 4; ++i)
#pragma unroll
            for (int j = 0; j < 6; ++j) acc[i][j] = fmaf(a[i], bb[j], acc[i][j]);
    }

    // ---- stage f16 hi/lo into LDS (5 planes x 4096 B)
    __syncthreads();
    char* sQh = qsm;
    char* sQl = qsm + 4096;
    char* sKh = qsm + 8192;
    char* sKl = qsm + 12288;
    char* sVh = qsm + 16384;
#pragma unroll
    for (int i = 0; i < 4; ++i) {
        int row = ty * 4 + i;
#pragma unroll
        for (int j = 0; j < 6; ++j) {
            int c = tx * 6 + j;
            float v = acc[i][j];
            if (c < 32) {
                v *= LOG2E;                       // logits in log2 domain
                _Float16 h16 = (_Float16)v;
                _Float16 l16 = (_Float16)(v - (float)h16);
                *(_Float16*)(sQh + row * 64 + c * 2) = h16;
                *(_Float16*)(sQl + row * 64 + c * 2) = l16;
            } else if (c < 64) {
                _Float16 h16 = (_Float16)v;
                _Float16 l16 = (_Float16)(v - (float)h16);
                int m = c - 32, q = m >> 3, wi = m & 7;
                int off = row * 64 + (((q + row) & 3) << 4) + wi * 2;
                *(_Float16*)(sKh + off) = h16;
                *(_Float16*)(sKl + off) = l16;
            } else {
                int d = c - 64, c8 = row >> 3, wi = row & 7;
                int off = d * 128 + (((c8 + d) & 7) << 4) + wi * 2;
                *(_Float16*)(sVh + off) = (_Float16)v;   // V: single f16
            }
        }
    }
    __syncthreads();

    // ---- coalesced stores: 5 planes x 4 KB contiguous
    size_t pb = eb * (size_t)Tv * 32 + (size_t)tile * 2048;   // f16 elems
    _Float16* dsts[5] = {Qh + pb, Ql + pb, Kh + pb, Kl + pb, Vth + pb};
#pragma unroll
    for (int pl = 0; pl < 5; ++pl)
        ((float4*)dsts[pl])[tid] = ((const float4*)(qsm + pl * 4096))[tid];

    // ---- fused mem: e==0 blocks compute memories for their 64 tokens
    if (e == 0 && tid < 64) {
        int t = b * Tv + tile * 64 + tid;       // token index < B*T
        const float4* xr = (const float4*)(x + (size_t)t * INv);
        float xv[32];
#pragma unroll
        for (int i = 0; i < 8; ++i) {
            float4 v = xr[i];
            xv[4*i] = v.x; xv[4*i+1] = v.y; xv[4*i+2] = v.z; xv[4*i+3] = v.w;
        }
        float qm[32];
#pragma unroll
        for (int m = 0; m < 32; ++m) qm[m] = 0.f;
        for (int i = 0; i < 32; ++i) {
            float xi = xv[i];
#pragma unroll
            for (int m4 = 0; m4 < 8; ++m4) {
                float4 wv = *(const float4*)&sIQ[i][m4 * 4];
                qm[4*m4]   = fmaf(xi, wv.x, qm[4*m4]);
                qm[4*m4+1] = fmaf(xi, wv.y, qm[4*m4+1]);
                qm[4*m4+2] = fmaf(xi, wv.z, qm[4*m4+2]);
                qm[4*m4+3] = fmaf(xi, wv.w, qm[4*m4+3]);
            }
        }
        float sc[20];
#pragma unroll
        for (int j = 0; j < 20; ++j) {
            float a2 = 0.f;
#pragma unroll
            for (int m = 0; m < 32; ++m) a2 = fmaf(qm[m], sM[j][m], a2);
            sc[j] = a2;
        }
        float mx = sc[0];
#pragma unroll
        for (int j = 1; j < 20; ++j) mx = fmaxf(mx, sc[j]);
        float psum = 0.f, p[20];
#pragma unroll
        for (int j = 0; j < 20; ++j) { p[j] = exp2f((sc[j] - mx) * LOG2E); psum += p[j]; }
        float inv = 1.0f / psum;
        float mo[32];
#pragma unroll
        for (int m = 0; m < 32; ++m) mo[m] = 0.f;
        for (int j = 0; j < 20; ++j) {
            float pj = p[j];
#pragma unroll
            for (int m = 0; m < 32; ++m) mo[m] = fmaf(pj, sM[j][m], mo[m]);
        }
        float4* outp = (float4*)(memout + (size_t)t * Mv);
#pragma unroll
        for (int m4 = 0; m4 < 8; ++m4) {
            float4 v;
            v.x = mo[4*m4] * inv; v.y = mo[4*m4+1] * inv;
            v.z = mo[4*m4+2] * inv; v.w = mo[4*m4+3] * inv;
            outp[m4] = v;
        }
    }
}

// ---------------------------------------------------------------------------
__device__ __forceinline__ void load_lds16(const _Float16* g, char* l) {
    __builtin_amdgcn_global_load_lds(
        (const __attribute__((address_space(1))) void*)g,
        (__attribute__((address_space(3))) void*)l, 16, 0, 0);
}

// ---------------------------------------------------------------------------
// Kernel 2: MFMA flash attention + cosine epilogue — R8/R10 kernel verbatim
// (measured 62-64 us across three rounds; every variant tried regressed).
// LDS: dbuf 2 x (Kh 4K | Kl 4K | Vh 4K) = 24576 + P 4x2048 XOR = 32768 B.
// ---------------------------------------------------------------------------
__global__ __launch_bounds__(256, 1) void attn_kernel(
    const _Float16* __restrict__ Qh, const _Float16* __restrict__ Ql,
    const _Float16* __restrict__ Kh, const _Float16* __restrict__ Kl,
    const _Float16* __restrict__ Vth,
    const float* __restrict__ memv,
    float* __restrict__ out)
{
    __shared__ __align__(16) char smem[32768];
    const int PW = 24576;

    int bid  = blockIdx.x;              // 768
    int xcd  = bid & 7;
    int slot = bid >> 3;                // 0..95
    int tile = slot & 31;
    int ebi  = xcd + ((slot >> 5) << 3);  // 0..23
    int e    = ebi >> 3;
    int b    = ebi & 7;
    int tid  = threadIdx.x;
    int lane = tid & 63;
    int w    = tid >> 6;
    int quad = lane >> 4;
    int l15  = lane & 15;
    size_t eb = (size_t)ebi;
    int q0 = tile * 64 + w * 16;

    size_t qoff = (eb * Tv + (size_t)(q0 + l15)) * 32 + quad * 8;
    half8 qH = *(const half8*)(Qh + qoff);
    half8 qL = *(const half8*)(Ql + qoff);

    float4v O0 = {0.f, 0.f, 0.f, 0.f};  // O[q=quad*4+r][d=l15]
    float4v O1 = {0.f, 0.f, 0.f, 0.f};  // O[q=quad*4+r][d=16+l15]
    float m_run = -3.0e38f;

    size_t ebOff = eb * (size_t)Tv * 32;
    const _Float16* gp[3] = {Kh + ebOff, Kl + ebOff, Vth + ebOff};

#pragma unroll
    for (int j = 0; j < 3; ++j) {
        int idx = w * 3 + j, p = idx >> 2, k = idx & 3;
        load_lds16(gp[p] + (size_t)k * 512 + lane * 8,
                   smem + p * 4096 + k * 1024);
    }

    for (int c = 0; c < 32; ++c) {
        int pb = c & 1;
        __syncthreads();
        if (c + 1 < 32) {
#pragma unroll
            for (int j = 0; j < 3; ++j) {
                int idx = w * 3 + j, p = idx >> 2, k = idx & 3;
                load_lds16(gp[p] + (size_t)(c + 1) * 2048 + k * 512 + lane * 8,
                           smem + (pb ^ 1) * 12288 + p * 4096 + k * 1024);
            }
        }
        const char* base = smem + pb * 12288;

        float s[16];
        float cmax = -3.0e38f;
#pragma unroll
        for (int tau = 0; tau < 4; ++tau) {
            int r = tau * 16 + l15;
            int sw = ((quad + r) & 3) << 4;
            half8 aH = *(const half8*)(base + r * 64 + sw);
            half8 aL = *(const half8*)(base + 4096 + r * 64 + sw);
            float4v acc = {0.f, 0.f, 0.f, 0.f};
            acc = __builtin_amdgcn_mfma_f32_16x16x32_f16(aH, qL, acc, 0, 0, 0);
            acc = __builtin_amdgcn_mfma_f32_16x16x32_f16(aL, qH, acc, 0, 0, 0);
            acc = __builtin_amdgcn_mfma_f32_16x16x32_f16(aH, qH, acc, 0, 0, 0);
#pragma unroll
            for (int r2 = 0; r2 < 4; ++r2) {
                s[tau * 4 + r2] = acc[r2];
                cmax = fmaxf(cmax, acc[r2]);
            }
        }
        cmax = fmaxf(cmax, __shfl_xor(cmax, 16));
        cmax = fmaxf(cmax, __shfl_xor(cmax, 32));
        float mNew  = fmaxf(m_run, cmax);
        float alpha = exp2f(m_run - mNew);
#pragma unroll
        for (int i = 0; i < 16; ++i)
            s[i] = exp2f(s[i] - mNew);
        m_run = mNew;

#pragma unroll
        for (int r = 0; r < 4; ++r) {
            float ar = __shfl(alpha, quad * 4 + r, 16);
            O0[r] *= ar;
            O1[r] *= ar;
        }

        char* pw = smem + PW + w * 2048 + l15 * 128;
        int xr = l15 & 7;
#pragma unroll
        for (int tau = 0; tau < 4; ++tau) {
            fp16x2 h01 = __builtin_amdgcn_cvt_pkrtz(s[tau*4+0], s[tau*4+1]);
            fp16x2 h23 = __builtin_amdgcn_cvt_pkrtz(s[tau*4+2], s[tau*4+3]);
            uint2 u;
            u.x = __builtin_bit_cast(unsigned int, h01);
            u.y = __builtin_bit_cast(unsigned int, h23);
            int bi = tau * 2 + (quad >> 1);          // 16-B block index
            *(uint2*)(pw + ((bi ^ xr) << 4) + (quad & 1) * 8) = u;
        }
        __asm__ volatile("" ::: "memory");

#pragma unroll
        for (int ks = 0; ks < 2; ++ks) {
            int swv = ((ks * 4 + quad + l15) & 7) << 4;
            half8 pA  = *(const half8*)(pw + (((ks * 4 + quad) ^ xr) << 4));
            half8 v0H = *(const half8*)(base + 8192 + l15 * 128 + swv);
            half8 v1H = *(const half8*)(base + 8192 + (16 + l15) * 128 + swv);
            O0 = __builtin_amdgcn_mfma_f32_16x16x32_f16(pA, v0H, O0, 0, 0, 0);
            O1 = __builtin_amdgcn_mfma_f32_16x16x32_f16(pA, v1H, O1, 0, 0, 0);
        }
    }

    // ---- epilogue: cosine(memories, O) — scale-invariant
    const float* mb = memv + (size_t)b * Tv * 32;
    float dotr[4], nor[4], nmr[4];
#pragma unroll
    for (int r = 0; r < 4; ++r) {
        int trow = q0 + quad * 4 + r;
        float mv0 = mb[(size_t)trow * 32 + l15];
        float mv1 = mb[(size_t)trow * 32 + 16 + l15];
        float d  = O0[r] * mv0 + O1[r] * mv1;
        float n  = O0[r] * O0[r] + O1[r] * O1[r];
        float nm = mv0 * mv0 + mv1 * mv1;
#pragma unroll
        for (int delta = 1; delta < 16; delta <<= 1) {
            d  += __shfl_xor(d,  delta);
            n  += __shfl_xor(n,  delta);
            nm += __shfl_xor(nm, delta);
        }
        dotr[r] = d; nor[r] = n; nmr[r] = nm;
    }
    if (l15 < 4) {
        int r = l15;
        float na = fmaxf(sqrtf(nmr[r]), 1e-8f);
        float nb = fmaxf(sqrtf(nor[r]), 1e-30f);
        float cosv = dotr[r] / (na * nb);
        int trow = q0 + quad * 4 + r;
        out[((size_t)b * Tv + trow) * Ev + e] = cosv;
    }
}

// ---------------------------------------------------------------------------
extern "C" void kernel_launch(void* const* d_in, const int* in_sizes, int n_in,
                              void* d_out, int out_size, void* d_ws, size_t ws_size,
                              hipStream_t stream) {
    const float* x      = (const float*)d_in[0];
    const float* hidden = (const float*)d_in[1];
    const float* memory = (const float*)d_in[2];
    const float* Wq     = (const float*)d_in[3];
    const float* Wk     = (const float*)d_in[4];
    const float* Wv     = (const float*)d_in[5];
    const float* iq     = (const float*)d_in[6];
    float* out          = (float*)d_out;           // [B,T,E] fp32

    char* ws = (char*)d_ws;
    // layout (bytes): memout f32 (2 MiB) | 5 f16 planes a 3 MiB = 17 MiB
    const size_t PLANE = (size_t)Ev * Bv * Tv * 32 * 2;   // 3,145,728 B
    float*    memout = (float*)ws;
    _Float16* Qh  = (_Float16*)(ws + 2097152);
    _Float16* Ql  = (_Float16*)(ws + 2097152 + PLANE);
    _Float16* Kh  = (_Float16*)(ws + 2097152 + 2 * PLANE);
    _Float16* Kl  = (_Float16*)(ws + 2097152 + 3 * PLANE);
    _Float16* Vth = (_Float16*)(ws + 2097152 + 4 * PLANE);

    qkv_kernel<<<Ev * Bv * (Tv / 64), 256, 0, stream>>>(hidden, Wq, Wk, Wv,
                                                        x, memory, iq,
                                                        Qh, Ql, Kh, Kl, Vth, memout);
    attn_kernel<<<Ev * Bv * (Tv / 64), 256, 0, stream>>>(Qh, Ql, Kh, Kl, Vth,
                                                         memout, out);
}